// Round 1
// baseline (655.253 us; speedup 1.0000x reference)
//
#include <hip/hip_runtime.h>
#include <cstdint>
#include <cstddef>

// Problem constants
#define B_    64
#define H_    8
#define N_    16384
#define M_    64
#define C_    1024
#define IVH_  198          // 3*M+6
#define J_    1584         // H*IVH
#define CHUNK_ 256
#define NCHUNK_ 64         // N/CHUNK

__device__ __forceinline__ float softplus_f(float x) {
    return (x > 20.f) ? x : log1pf(__expf(x));
}
__device__ __forceinline__ float sigmoid_f(float x) {
    return 1.f / (1.f + __expf(-x));
}

// ---------------------------------------------------------------------------
// Kernel 1: iv = x @ W  (bias folded in later). Partial-c atomic accumulate.
// grid (25 jtiles, 16 bgroups of 4, 2 cchunks of 512), block 64.
__global__ void k_gemm(const float* __restrict__ x, const float* __restrict__ W,
                       float* __restrict__ iv) {
    int lane = threadIdx.x;
    int j = blockIdx.x * 64 + lane;
    int bg = blockIdx.y;            // 4 b's per block
    int c0 = blockIdx.z * 512;
    bool valid = (j < J_);
    const float* x0 = x + (size_t)(bg * 4 + 0) * C_;
    const float* x1 = x + (size_t)(bg * 4 + 1) * C_;
    const float* x2 = x + (size_t)(bg * 4 + 2) * C_;
    const float* x3 = x + (size_t)(bg * 4 + 3) * C_;
    float a0 = 0.f, a1 = 0.f, a2 = 0.f, a3 = 0.f;
    #pragma unroll 4
    for (int c = c0; c < c0 + 512; ++c) {
        float wv = valid ? W[(size_t)c * J_ + j] : 0.f;
        a0 = fmaf(x0[c], wv, a0);
        a1 = fmaf(x1[c], wv, a1);
        a2 = fmaf(x2[c], wv, a2);
        a3 = fmaf(x3[c], wv, a3);
    }
    if (valid) {
        atomicAdd(&iv[(size_t)(bg * 4 + 0) * J_ + j], a0);
        atomicAdd(&iv[(size_t)(bg * 4 + 1) * J_ + j], a1);
        atomicAdd(&iv[(size_t)(bg * 4 + 2) * J_ + j], a2);
        atomicAdd(&iv[(size_t)(bg * 4 + 3) * J_ + j], a3);
    }
}

// ---------------------------------------------------------------------------
// Kernel 2: per-(b,h) parameter extraction. grid 512 blocks, block 64 (1 wave).
__global__ void k_params(const float* __restrict__ iv, const float* __restrict__ bias,
                         float* __restrict__ kbuf, float* __restrict__ P,
                         float* __restrict__ out_e, float* __restrict__ out_a) {
    int bh = blockIdx.x;
    int m  = threadIdx.x;              // 0..63
    int b = bh >> 3, h = bh & 7;
    const float* row = iv + (size_t)b * J_ + h * IVH_;
    const float* bb  = bias + h * IVH_;
    float kv = row[m] + bb[m];
    kbuf[(size_t)bh * 64 + m] = kv;
    float s = kv * kv;
    #pragma unroll
    for (int o = 32; o > 0; o >>= 1) s += __shfl_down(s, o, 64);
    // e and a outputs
    float ev = row[70 + m] + bb[70 + m];            // M+6 = 70
    out_e[(size_t)bh * 64 + m] = sigmoid_f(ev);
    out_a[(size_t)bh * 64 + m] = row[134 + m] + bb[134 + m];  // 2M+6 = 134
    if (m == 0) {
        float knorm = sqrtf(s);
        float v0 = row[64] + bb[64];
        float v1 = row[65] + bb[65];
        float v2 = row[66] + bb[66];
        float v3 = row[67] + bb[67];
        float v4 = row[68] + bb[68];
        float v5 = row[69] + bb[69];
        float beta = softplus_f(v0);
        float g = sigmoid_f(v1);
        float mx = fmaxf(v2, fmaxf(v3, v4));
        float e2 = __expf(v2 - mx), e3 = __expf(v3 - mx), e4 = __expf(v4 - mx);
        float inv = 1.f / (e2 + e3 + e4);
        float gamma = 1.f + softplus_f(v5);
        float* p = P + (size_t)bh * 8;
        p[0] = knorm; p[1] = beta; p[2] = g;
        p[3] = e2 * inv; p[4] = e3 * inv; p[5] = e4 * inv;
        p[6] = gamma;
    }
}

// ---------------------------------------------------------------------------
// Kernel 3 (pass A): z = beta*cos, per-chunk softmax partials.
// grid (NCHUNK, B), block 256 (1 row per thread).
__global__ __launch_bounds__(256) void k_passA(
        const float* __restrict__ mem, const float* __restrict__ kbuf,
        const float* __restrict__ P, float* __restrict__ z,
        float* __restrict__ pmax, float* __restrict__ psum) {
    int b = blockIdx.y;
    int n = (blockIdx.x << 8) + threadIdx.x;
    const float4* rowp = (const float4*)(mem + ((size_t)b * N_ + n) * M_);
    float4 r[16];
    #pragma unroll
    for (int i = 0; i < 16; ++i) r[i] = rowp[i];
    float rn = 0.f;
    #pragma unroll
    for (int i = 0; i < 16; ++i)
        rn += r[i].x * r[i].x + r[i].y * r[i].y + r[i].z * r[i].z + r[i].w * r[i].w;
    rn = sqrtf(rn);
    float zv[8];
    #pragma unroll
    for (int h = 0; h < 8; ++h) {
        const float* kh = kbuf + (((size_t)b * 8 + h) << 6);
        float acc = 0.f;
        #pragma unroll
        for (int i = 0; i < 16; ++i) {
            acc = fmaf(kh[4 * i + 0], r[i].x, acc);
            acc = fmaf(kh[4 * i + 1], r[i].y, acc);
            acc = fmaf(kh[4 * i + 2], r[i].z, acc);
            acc = fmaf(kh[4 * i + 3], r[i].w, acc);
        }
        const float* p = P + (((size_t)b * 8 + h) << 3);
        float knorm = p[0], beta = p[1];
        float zz = beta * acc / (knorm * rn + 1e-16f);
        zv[h] = zz;
        z[(((size_t)b * 8 + h) << 14) + n] = zz;
    }
    __shared__ float zl[8][256];
    #pragma unroll
    for (int h = 0; h < 8; ++h) zl[h][threadIdx.x] = zv[h];
    __syncthreads();
    int w = threadIdx.x >> 6, lane = threadIdx.x & 63;
    #pragma unroll
    for (int q = 0; q < 2; ++q) {
        int h = w * 2 + q;
        float a0 = zl[h][lane], a1 = zl[h][lane + 64];
        float a2 = zl[h][lane + 128], a3 = zl[h][lane + 192];
        float mx = fmaxf(fmaxf(a0, a1), fmaxf(a2, a3));
        #pragma unroll
        for (int o = 32; o > 0; o >>= 1) mx = fmaxf(mx, __shfl_down(mx, o, 64));
        mx = __shfl(mx, 0, 64);
        float se = __expf(a0 - mx) + __expf(a1 - mx) + __expf(a2 - mx) + __expf(a3 - mx);
        #pragma unroll
        for (int o = 32; o > 0; o >>= 1) se += __shfl_down(se, o, 64);
        if (lane == 0) {
            pmax[(((size_t)b * 8 + h) << 6) + blockIdx.x] = mx;
            psum[(((size_t)b * 8 + h) << 6) + blockIdx.x] = se;
        }
    }
}

// ---------------------------------------------------------------------------
// Kernel 4: reduce per-chunk softmax partials -> (Mx, 1/S) per (b,h).
// grid 128 blocks x 256 (one wave per bh).
__global__ void k_stats(const float* __restrict__ pmax, const float* __restrict__ psum,
                        float* __restrict__ stats) {
    int bh = blockIdx.x * 4 + (threadIdx.x >> 6);
    int lane = threadIdx.x & 63;
    float m = pmax[((size_t)bh << 6) + lane];
    float s = psum[((size_t)bh << 6) + lane];
    float mx = m;
    #pragma unroll
    for (int o = 32; o > 0; o >>= 1) mx = fmaxf(mx, __shfl_down(mx, o, 64));
    mx = __shfl(mx, 0, 64);
    float sc = s * __expf(m - mx);
    #pragma unroll
    for (int o = 32; o > 0; o >>= 1) sc += __shfl_down(sc, o, 64);
    if (lane == 0) { stats[bh * 2] = mx; stats[bh * 2 + 1] = 1.f / sc; }
}

// ---------------------------------------------------------------------------
// Kernel 5 (pass B): wc -> wg -> ws -> wp; write unnormalized wp to out_w;
// accumulate sumwp and readAcc = sum_n wp*mem via atomics.
// grid (NCHUNK, B), block 256. LDS: wp[256][8] + union{wg[8][258], racc[8192]}.
__global__ __launch_bounds__(256) void k_passB(
        const float* __restrict__ mem, const float* __restrict__ z,
        const float* __restrict__ wprev, const float* __restrict__ P,
        const float* __restrict__ stats, float* __restrict__ out_w,
        float* __restrict__ sumwp, float* __restrict__ readAcc) {
    __shared__ float smem[2048 + 8192];   // 40 KB
    float* wp_s = smem;                   // [256][8]
    float* wgl  = smem + 2048;            // [8][258]  (phase 1 only)
    float* racc = smem + 2048;            // [8192]    (phase 2, overlaps wgl)

    int t = threadIdx.x;
    int b = blockIdx.y;
    int n0 = blockIdx.x << 8;
    int n = n0 + t;

    // phase 1: wg into LDS (with circular halo)
    #pragma unroll
    for (int h = 0; h < 8; ++h) {
        size_t bh = (size_t)b * 8 + h;
        float Mx = stats[bh * 2], iS = stats[bh * 2 + 1];
        float g = P[bh * 8 + 2];
        float wc = __expf(z[(bh << 14) + n] - Mx) * iS;
        wgl[h * 258 + t + 1] = fmaf(g, wc, (1.f - g) * wprev[(bh << 14) + n]);
    }
    if (t < 2) {
        int nh   = (t == 0) ? ((n0 + N_ - 1) & (N_ - 1)) : ((n0 + 256) & (N_ - 1));
        int slot = (t == 0) ? 0 : 257;
        #pragma unroll
        for (int h = 0; h < 8; ++h) {
            size_t bh = (size_t)b * 8 + h;
            float Mx = stats[bh * 2], iS = stats[bh * 2 + 1];
            float g = P[bh * 8 + 2];
            float wc = __expf(z[(bh << 14) + nh] - Mx) * iS;
            wgl[h * 258 + slot] = fmaf(g, wc, (1.f - g) * wprev[(bh << 14) + nh]);
        }
    }
    __syncthreads();

    // phase 1b: shift + sharpen -> wp
    float wpv[8];
    #pragma unroll
    for (int h = 0; h < 8; ++h) {
        size_t bh = (size_t)b * 8 + h;
        float s0 = P[bh * 8 + 3], s1 = P[bh * 8 + 4], s2 = P[bh * 8 + 5];
        float gam = P[bh * 8 + 6];
        float wsv = s0 * wgl[h * 258 + t] + s1 * wgl[h * 258 + t + 1]
                  + s2 * wgl[h * 258 + t + 2];
        float v = __powf(wsv, gam);
        wpv[h] = v;
        out_w[(bh << 14) + n] = v;      // unnormalized; k_norm rescales
    }
    ((float4*)(wp_s + t * 8))[0] = make_float4(wpv[0], wpv[1], wpv[2], wpv[3]);
    ((float4*)(wp_s + t * 8))[1] = make_float4(wpv[4], wpv[5], wpv[6], wpv[7]);
    __syncthreads();

    // sumwp reduce: wave w handles h = 2w, 2w+1
    int wv = t >> 6, lane = t & 63;
    #pragma unroll
    for (int q = 0; q < 2; ++q) {
        int h = wv * 2 + q;
        float s = wp_s[lane * 8 + h] + wp_s[(lane + 64) * 8 + h]
                + wp_s[(lane + 128) * 8 + h] + wp_s[(lane + 192) * 8 + h];
        #pragma unroll
        for (int o = 32; o > 0; o >>= 1) s += __shfl_down(s, o, 64);
        if (lane == 0) atomicAdd(&sumwp[b * 8 + h], s);
    }

    // phase 2: readAcc partials, register-blocked 8h x 4m per thread
    int sub = t >> 4, mq = t & 15;
    const float4* basep = (const float4*)(mem + ((size_t)b * N_ + n0) * M_);
    float4 acc[8];
    #pragma unroll
    for (int h = 0; h < 8; ++h) acc[h] = make_float4(0.f, 0.f, 0.f, 0.f);
    #pragma unroll
    for (int rr = 0; rr < 16; ++rr) {
        int row = sub * 16 + rr;
        float4 mv = basep[row * 16 + mq];
        float4 wA = ((const float4*)(wp_s + row * 8))[0];
        float4 wB = ((const float4*)(wp_s + row * 8))[1];
        float wv8[8] = {wA.x, wA.y, wA.z, wA.w, wB.x, wB.y, wB.z, wB.w};
        #pragma unroll
        for (int h = 0; h < 8; ++h) {
            acc[h].x = fmaf(wv8[h], mv.x, acc[h].x);
            acc[h].y = fmaf(wv8[h], mv.y, acc[h].y);
            acc[h].z = fmaf(wv8[h], mv.z, acc[h].z);
            acc[h].w = fmaf(wv8[h], mv.w, acc[h].w);
        }
    }
    float* rb = racc + (size_t)(sub * 16 + mq) * 32;
    #pragma unroll
    for (int h = 0; h < 8; ++h) ((float4*)rb)[h] = acc[h];
    __syncthreads();
    if (t < 128) {
        int h = t & 7, m2 = t >> 3;
        float4 s4 = make_float4(0.f, 0.f, 0.f, 0.f);
        #pragma unroll
        for (int sb = 0; sb < 16; ++sb) {
            float4 v = ((const float4*)(racc + (size_t)(sb * 16 + m2) * 32))[h];
            s4.x += v.x; s4.y += v.y; s4.z += v.z; s4.w += v.w;
        }
        float* dst = readAcc + (((size_t)b * 8 + h) << 6) + m2 * 4;
        atomicAdd(dst + 0, s4.x);
        atomicAdd(dst + 1, s4.y);
        atomicAdd(dst + 2, s4.z);
        atomicAdd(dst + 3, s4.w);
    }
}

// ---------------------------------------------------------------------------
// Kernel 6: normalize w in place. grid 8192 x 256, float4 per thread.
__global__ void k_norm(float* __restrict__ out_w, const float* __restrict__ sumwp) {
    size_t idx = (size_t)blockIdx.x * 256 + threadIdx.x;  // float4 index
    int bh = (int)((idx * 4) >> 14);
    float inv = 1.f / (sumwp[bh] + 1e-16f);
    float4* p = (float4*)out_w + idx;
    float4 v = *p;
    v.x *= inv; v.y *= inv; v.z *= inv; v.w *= inv;
    *p = v;
}

// Kernel 7: read_data = readAcc / (sumwp + eps). grid 128 x 256.
__global__ void k_read(const float* __restrict__ readAcc, const float* __restrict__ sumwp,
                       float* __restrict__ out_rd) {
    int i = blockIdx.x * 256 + threadIdx.x;  // 32768 total
    int bh = i >> 6;
    out_rd[i] = readAcc[i] / (sumwp[bh] + 1e-16f);
}

// ---------------------------------------------------------------------------
extern "C" void kernel_launch(void* const* d_in, const int* in_sizes, int n_in,
                              void* d_out, int out_size, void* d_ws, size_t ws_size,
                              hipStream_t stream) {
    const float* x     = (const float*)d_in[0];
    const float* mem   = (const float*)d_in[1];
    const float* wprev = (const float*)d_in[2];
    const float* W     = (const float*)d_in[3];
    const float* bias  = (const float*)d_in[4];

    float* out   = (float*)d_out;
    float* out_rd = out;                         // 32768
    float* out_w  = out + 32768;                 // 8388608
    float* out_e  = out + 32768 + 8388608;       // 32768
    float* out_a  = out_e + 32768;               // 32768

    float* ws     = (float*)d_ws;
    float* iv      = ws;                 // 101376
    float* kbuf    = iv + 101376;        // 32768
    float* P       = kbuf + 32768;       // 4096
    float* zbuf    = P + 4096;           // 8388608
    float* pmax    = zbuf + 8388608;     // 32768
    float* psum    = pmax + 32768;       // 32768
    float* stats   = psum + 32768;       // 1024
    float* sumwp   = stats + 1024;       // 512
    float* readAcc = sumwp + 512;        // 32768  (contiguous with sumwp)

    hipMemsetAsync(iv, 0, (size_t)101376 * 4, stream);
    hipMemsetAsync(sumwp, 0, (size_t)(512 + 32768) * 4, stream);

    k_gemm  <<<dim3(25, 16, 2), 64, 0, stream>>>(x, W, iv);
    k_params<<<512, 64, 0, stream>>>(iv, bias, kbuf, P, out_e, out_a);
    k_passA <<<dim3(NCHUNK_, B_), 256, 0, stream>>>(mem, kbuf, P, zbuf, pmax, psum);
    k_stats <<<128, 256, 0, stream>>>(pmax, psum, stats);
    k_passB <<<dim3(NCHUNK_, B_), 256, 0, stream>>>(mem, zbuf, wprev, P, stats,
                                                    out_w, sumwp, readAcc);
    k_norm  <<<8192, 256, 0, stream>>>(out_w, sumwp);
    k_read  <<<128, 256, 0, stream>>>(readAcc, sumwp, out_rd);
}

// Round 2
// 540.400 us; speedup vs baseline: 1.2125x; 1.2125x over previous
//
#include <hip/hip_runtime.h>
#include <cstdint>
#include <cstddef>

// Problem constants
#define B_    64
#define H_    8
#define N_    16384
#define M_    64
#define C_    1024
#define IVH_  198          // 3*M+6
#define J_    1584         // H*IVH
#define NCHUNK_ 64         // N/256

__device__ __forceinline__ float softplus_f(float x) {
    return (x > 20.f) ? x : log1pf(__expf(x));
}
__device__ __forceinline__ float sigmoid_f(float x) {
    return 1.f / (1.f + __expf(-x));
}

// ---------------------------------------------------------------------------
// Kernel 1: iv = x @ W. 16 b's per block (x loads are wave-uniform -> s_load).
// grid (25 jtiles, 4 bgroups, 8 cchunks of 128), block 64.
__global__ __launch_bounds__(64) void k_gemm(const float* __restrict__ x,
                                             const float* __restrict__ W,
                                             float* __restrict__ iv) {
    int lane = threadIdx.x;
    int j = blockIdx.x * 64 + lane;
    bool valid = (j < J_);
    int b0 = blockIdx.y * 16;
    int c0 = blockIdx.z * 128;
    const float* xb = x + (size_t)b0 * C_;
    float acc[16];
    #pragma unroll
    for (int i = 0; i < 16; ++i) acc[i] = 0.f;
    #pragma unroll 2
    for (int c = c0; c < c0 + 128; ++c) {
        float wv = valid ? W[(size_t)c * J_ + j] : 0.f;
        #pragma unroll
        for (int bi = 0; bi < 16; ++bi)
            acc[bi] = fmaf(xb[(size_t)bi * C_ + c], wv, acc[bi]);
    }
    if (valid) {
        #pragma unroll
        for (int bi = 0; bi < 16; ++bi)
            atomicAdd(&iv[(size_t)(b0 + bi) * J_ + j], acc[bi]);
    }
}

// ---------------------------------------------------------------------------
// Kernel 2: per-(b,h) parameter extraction. grid 512 blocks, block 64.
__global__ void k_params(const float* __restrict__ iv, const float* __restrict__ bias,
                         float* __restrict__ kbuf, float* __restrict__ P,
                         float* __restrict__ out_e, float* __restrict__ out_a) {
    int bh = blockIdx.x;
    int m  = threadIdx.x;              // 0..63
    int b = bh >> 3, h = bh & 7;
    const float* row = iv + (size_t)b * J_ + h * IVH_;
    const float* bb  = bias + h * IVH_;
    float kv = row[m] + bb[m];
    kbuf[(size_t)bh * 64 + m] = kv;
    float s = kv * kv;
    #pragma unroll
    for (int o = 32; o > 0; o >>= 1) s += __shfl_down(s, o, 64);
    float ev = row[70 + m] + bb[70 + m];            // M+6 = 70
    out_e[(size_t)bh * 64 + m] = sigmoid_f(ev);
    out_a[(size_t)bh * 64 + m] = row[134 + m] + bb[134 + m];  // 2M+6 = 134
    if (m == 0) {
        float knorm = sqrtf(s);
        float v0 = row[64] + bb[64];
        float v1 = row[65] + bb[65];
        float v2 = row[66] + bb[66];
        float v3 = row[67] + bb[67];
        float v4 = row[68] + bb[68];
        float v5 = row[69] + bb[69];
        float beta = softplus_f(v0);
        float g = sigmoid_f(v1);
        float mx = fmaxf(v2, fmaxf(v3, v4));
        float e2 = __expf(v2 - mx), e3 = __expf(v3 - mx), e4 = __expf(v4 - mx);
        float inv = 1.f / (e2 + e3 + e4);
        float gamma = 1.f + softplus_f(v5);
        float* p = P + (size_t)bh * 8;
        p[0] = knorm; p[1] = beta; p[2] = g;
        p[3] = e2 * inv; p[4] = e3 * inv; p[5] = e4 * inv;
        p[6] = gamma;
    }
}

// ---------------------------------------------------------------------------
// Kernel 3 (pass A): coalesced 16-lanes-per-row; butterfly dot reduce;
// z = beta*cos staged in LDS then stored coalesced; per-chunk softmax partials.
// grid (NCHUNK, B), block 256.
__global__ __launch_bounds__(256, 4) void k_passA(
        const float* __restrict__ mem, const float* __restrict__ kbuf,
        const float* __restrict__ P, float* __restrict__ z,
        float* __restrict__ pmax, float* __restrict__ psum) {
    __shared__ float zl[8 * 257];      // [h*257 + row]
    int t = threadIdx.x;
    int b = blockIdx.y;
    int n0 = blockIdx.x << 8;
    int w = t >> 6, lane = t & 63, sub = lane >> 4, mq = lane & 15;

    float4 kreg[8];
    #pragma unroll
    for (int h = 0; h < 8; ++h)
        kreg[h] = *(const float4*)(kbuf + (((size_t)b * 8 + h) << 6) + mq * 4);
    float beta = 0.f, knorm = 1.f;
    if (mq < 8) {
        const float* p = P + (((size_t)b * 8 + mq) << 3);
        knorm = p[0]; beta = p[1];
    }
    const float* mb = mem + ((size_t)b * N_ + n0) * M_;

    #pragma unroll
    for (int rr = 0; rr < 16; ++rr) {
        int row = (w << 6) + (rr << 2) + sub;
        float4 mv = *(const float4*)(mb + (size_t)row * M_ + mq * 4);
        float pr[9];
        #pragma unroll
        for (int h = 0; h < 8; ++h)
            pr[h] = kreg[h].x * mv.x + kreg[h].y * mv.y
                  + kreg[h].z * mv.z + kreg[h].w * mv.w;
        pr[8] = mv.x * mv.x + mv.y * mv.y + mv.z * mv.z + mv.w * mv.w;
        #pragma unroll
        for (int o = 1; o < 16; o <<= 1) {
            #pragma unroll
            for (int i = 0; i < 9; ++i) pr[i] += __shfl_xor(pr[i], o, 64);
        }
        if (mq < 8) {
            float rn = sqrtf(pr[8]);
            zl[mq * 257 + row] = beta * pr[mq] / (knorm * rn + 1e-16f);
        }
    }
    __syncthreads();

    // global z store (coalesced per h)
    #pragma unroll
    for (int h = 0; h < 8; ++h)
        z[(((size_t)b * 8 + h) << 14) + n0 + t] = zl[h * 257 + t];

    // chunk softmax partials: wave w handles h = 2w, 2w+1
    #pragma unroll
    for (int q = 0; q < 2; ++q) {
        int h = w * 2 + q;
        float a0 = zl[h * 257 + lane],       a1 = zl[h * 257 + lane + 64];
        float a2 = zl[h * 257 + lane + 128], a3 = zl[h * 257 + lane + 192];
        float mx = fmaxf(fmaxf(a0, a1), fmaxf(a2, a3));
        #pragma unroll
        for (int o = 32; o > 0; o >>= 1) mx = fmaxf(mx, __shfl_down(mx, o, 64));
        mx = __shfl(mx, 0, 64);
        float se = __expf(a0 - mx) + __expf(a1 - mx) + __expf(a2 - mx) + __expf(a3 - mx);
        #pragma unroll
        for (int o = 32; o > 0; o >>= 1) se += __shfl_down(se, o, 64);
        if (lane == 0) {
            pmax[(((size_t)b * 8 + h) << 6) + blockIdx.x] = mx;
            psum[(((size_t)b * 8 + h) << 6) + blockIdx.x] = se;
        }
    }
}

// ---------------------------------------------------------------------------
// Kernel 4: reduce per-chunk softmax partials -> (Mx, 1/S) per (b,h).
__global__ void k_stats(const float* __restrict__ pmax, const float* __restrict__ psum,
                        float* __restrict__ stats) {
    int bh = blockIdx.x * 4 + (threadIdx.x >> 6);
    int lane = threadIdx.x & 63;
    float m = pmax[((size_t)bh << 6) + lane];
    float s = psum[((size_t)bh << 6) + lane];
    float mx = m;
    #pragma unroll
    for (int o = 32; o > 0; o >>= 1) mx = fmaxf(mx, __shfl_down(mx, o, 64));
    mx = __shfl(mx, 0, 64);
    float sc = s * __expf(m - mx);
    #pragma unroll
    for (int o = 32; o > 0; o >>= 1) sc += __shfl_down(sc, o, 64);
    if (lane == 0) { stats[bh * 2] = mx; stats[bh * 2 + 1] = 1.f / sc; }
}

// ---------------------------------------------------------------------------
// Kernel 5 (pass B): wc -> wg -> ws -> wp (write unnormalized to out_w),
// sumwp via register butterfly, readAcc via coalesced mem + shuffle reduce.
// LDS: wp_s[256*12] (12.0 KB) + union{wgl[8*258], racc2[2048]} (8.25 KB) + sums (0.13 KB)
__global__ __launch_bounds__(256, 4) void k_passB(
        const float* __restrict__ mem, const float* __restrict__ z,
        const float* __restrict__ wprev, const float* __restrict__ P,
        const float* __restrict__ stats, float* __restrict__ out_w,
        float* __restrict__ sumwp, float* __restrict__ readAcc) {
    __shared__ float smem[3072 + 2064 + 32];
    float* wp_s  = smem;               // [row*12 + 0..7]
    float* wgl   = smem + 3072;        // [h*258 + idx], idx 0..257 (phase 1)
    float* racc2 = smem + 3072;        // [2048] (phase 2, overlaps wgl)
    float* sums  = smem + 3072 + 2064; // [w*8+h]

    int t = threadIdx.x;
    int b = blockIdx.y;
    int n0 = blockIdx.x << 8;
    int n = n0 + t;
    int w = t >> 6, lane = t & 63, sub = lane >> 4, mq = lane & 15;

    // phase 1: wg into LDS (with circular halo)
    #pragma unroll
    for (int h = 0; h < 8; ++h) {
        size_t bh = (size_t)b * 8 + h;
        float Mx = stats[bh * 2], iS = stats[bh * 2 + 1];
        float g = P[bh * 8 + 2];
        float wc = __expf(z[(bh << 14) + n] - Mx) * iS;
        wgl[h * 258 + t + 1] = fmaf(g, wc, (1.f - g) * wprev[(bh << 14) + n]);
    }
    if (t < 2) {
        int nh   = (t == 0) ? ((n0 + N_ - 1) & (N_ - 1)) : ((n0 + 256) & (N_ - 1));
        int slot = (t == 0) ? 0 : 257;
        #pragma unroll
        for (int h = 0; h < 8; ++h) {
            size_t bh = (size_t)b * 8 + h;
            float Mx = stats[bh * 2], iS = stats[bh * 2 + 1];
            float g = P[bh * 8 + 2];
            float wc = __expf(z[(bh << 14) + nh] - Mx) * iS;
            wgl[h * 258 + slot] = fmaf(g, wc, (1.f - g) * wprev[(bh << 14) + nh]);
        }
    }
    __syncthreads();

    // phase 1b: shift + sharpen -> wp
    float wpv[8];
    #pragma unroll
    for (int h = 0; h < 8; ++h) {
        size_t bh = (size_t)b * 8 + h;
        float s0 = P[bh * 8 + 3], s1 = P[bh * 8 + 4], s2 = P[bh * 8 + 5];
        float gam = P[bh * 8 + 6];
        float wsv = s0 * wgl[h * 258 + t] + s1 * wgl[h * 258 + t + 1]
                  + s2 * wgl[h * 258 + t + 2];
        float v = __powf(wsv, gam);
        wpv[h] = v;
        out_w[(bh << 14) + n] = v;      // unnormalized; k_norm rescales
    }
    // sumwp: register butterfly per wave
    #pragma unroll
    for (int h = 0; h < 8; ++h) {
        float s = wpv[h];
        #pragma unroll
        for (int o = 32; o > 0; o >>= 1) s += __shfl_down(s, o, 64);
        if (lane == 0) sums[w * 8 + h] = s;
    }
    // stage wp (stride 12: 16B-aligned, <=2-way bank alias)
    *(float4*)(wp_s + t * 12)     = make_float4(wpv[0], wpv[1], wpv[2], wpv[3]);
    *(float4*)(wp_s + t * 12 + 4) = make_float4(wpv[4], wpv[5], wpv[6], wpv[7]);
    __syncthreads();
    if (t < 8)
        atomicAdd(&sumwp[b * 8 + t], sums[t] + sums[8 + t] + sums[16 + t] + sums[24 + t]);

    // phase 2: coalesced weighted read, 16 lanes per row
    float4 acc[8];
    #pragma unroll
    for (int h = 0; h < 8; ++h) acc[h] = make_float4(0.f, 0.f, 0.f, 0.f);
    const float* mb = mem + ((size_t)b * N_ + n0) * M_;
    #pragma unroll
    for (int rr = 0; rr < 16; ++rr) {
        int row = (w << 6) + (rr << 2) + sub;
        float4 mv = *(const float4*)(mb + (size_t)row * M_ + mq * 4);
        float4 wA = *(const float4*)(wp_s + row * 12);
        float4 wB = *(const float4*)(wp_s + row * 12 + 4);
        float wv8[8] = {wA.x, wA.y, wA.z, wA.w, wB.x, wB.y, wB.z, wB.w};
        #pragma unroll
        for (int h = 0; h < 8; ++h) {
            acc[h].x = fmaf(wv8[h], mv.x, acc[h].x);
            acc[h].y = fmaf(wv8[h], mv.y, acc[h].y);
            acc[h].z = fmaf(wv8[h], mv.z, acc[h].z);
            acc[h].w = fmaf(wv8[h], mv.w, acc[h].w);
        }
    }
    // reduce across sub (4 groups) within wave
    #pragma unroll
    for (int h = 0; h < 8; ++h) {
        #pragma unroll
        for (int o = 32; o >= 16; o >>= 1) {
            acc[h].x += __shfl_down(acc[h].x, o, 64);
            acc[h].y += __shfl_down(acc[h].y, o, 64);
            acc[h].z += __shfl_down(acc[h].z, o, 64);
            acc[h].w += __shfl_down(acc[h].w, o, 64);
        }
    }
    if (lane < 16) {
        #pragma unroll
        for (int h = 0; h < 8; ++h)
            *(float4*)(racc2 + ((w * 8 + h) << 6) + mq * 4) = acc[h];
    }
    __syncthreads();
    // final: sum 4 wave partials, atomic to readAcc (coalesced)
    #pragma unroll
    for (int r = 0; r < 2; ++r) {
        int idx = r * 256 + t;
        float s = racc2[idx] + racc2[512 + idx] + racc2[1024 + idx] + racc2[1536 + idx];
        atomicAdd(&readAcc[(size_t)b * 512 + idx], s);
    }
}

// ---------------------------------------------------------------------------
// Kernel 6: normalize w in place. grid 8192 x 256, float4 per thread.
__global__ void k_norm(float* __restrict__ out_w, const float* __restrict__ sumwp) {
    size_t idx = (size_t)blockIdx.x * 256 + threadIdx.x;  // float4 index
    int bh = (int)((idx * 4) >> 14);
    float inv = 1.f / (sumwp[bh] + 1e-16f);
    float4* p = (float4*)out_w + idx;
    float4 v = *p;
    v.x *= inv; v.y *= inv; v.z *= inv; v.w *= inv;
    *p = v;
}

// Kernel 7: read_data = readAcc / (sumwp + eps). grid 128 x 256.
__global__ void k_read(const float* __restrict__ readAcc, const float* __restrict__ sumwp,
                       float* __restrict__ out_rd) {
    int i = blockIdx.x * 256 + threadIdx.x;  // 32768 total
    int bh = i >> 6;
    out_rd[i] = readAcc[i] / (sumwp[bh] + 1e-16f);
}

// ---------------------------------------------------------------------------
extern "C" void kernel_launch(void* const* d_in, const int* in_sizes, int n_in,
                              void* d_out, int out_size, void* d_ws, size_t ws_size,
                              hipStream_t stream) {
    const float* x     = (const float*)d_in[0];
    const float* mem   = (const float*)d_in[1];
    const float* wprev = (const float*)d_in[2];
    const float* W     = (const float*)d_in[3];
    const float* bias  = (const float*)d_in[4];

    float* out   = (float*)d_out;
    float* out_rd = out;                         // 32768
    float* out_w  = out + 32768;                 // 8388608
    float* out_e  = out + 32768 + 8388608;       // 32768
    float* out_a  = out_e + 32768;               // 32768

    float* ws     = (float*)d_ws;
    float* iv      = ws;                 // 101376
    float* kbuf    = iv + 101376;        // 32768
    float* P       = kbuf + 32768;       // 4096
    float* zbuf    = P + 4096;           // 8388608
    float* pmax    = zbuf + 8388608;     // 32768
    float* psum    = pmax + 32768;       // 32768
    float* stats   = psum + 32768;       // 1024
    float* sumwp   = stats + 1024;       // 512
    float* readAcc = sumwp + 512;        // 32768  (contiguous with sumwp)

    hipMemsetAsync(iv, 0, (size_t)101376 * 4, stream);
    hipMemsetAsync(sumwp, 0, (size_t)(512 + 32768) * 4, stream);

    k_gemm  <<<dim3(25, 4, 8), 64, 0, stream>>>(x, W, iv);
    k_params<<<512, 64, 0, stream>>>(iv, bias, kbuf, P, out_e, out_a);
    k_passA <<<dim3(NCHUNK_, B_), 256, 0, stream>>>(mem, kbuf, P, zbuf, pmax, psum);
    k_stats <<<128, 256, 0, stream>>>(pmax, psum, stats);
    k_passB <<<dim3(NCHUNK_, B_), 256, 0, stream>>>(mem, zbuf, wprev, P, stats,
                                                    out_w, sumwp, readAcc);
    k_norm  <<<8192, 256, 0, stream>>>(out_w, sumwp);
    k_read  <<<128, 256, 0, stream>>>(readAcc, sumwp, out_rd);
}